// Round 2
// baseline (121.847 us; speedup 1.0000x reference)
//
#include <hip/hip_runtime.h>

#define B_DIM 256
#define T_DIM 2048
#define D_DIM 128

// Fused single-pass kernel. One block = one (batch, t-chunk).
//   p_t = exp(tanh(x[t,:]·W + b[t]))   (tanh in [-1,1] -> no softmax max needed)
//   s   = sum_t p_t ; o[d] = sum_t p_t * x[t,d]
// Each lane float4-loads 16B: a wave covers TWO t-rows per load instruction
// (lanes 0-31 -> row t, lanes 32-63 -> row t+1). Row dot reduced with 5
// shfl_xor steps (stays inside each 32-lane half). Per-lane float4 "o" acc.
// Last block per batch (device-scope counter) combines the C partials in
// fixed order (deterministic) and writes out = o/s.
template <int NWAVES, bool FINAL>
__global__ __launch_bounds__(NWAVES * 64) void attn_pass1(
    const float* __restrict__ x, const float* __restrict__ W,
    const float* __restrict__ bb, float* __restrict__ o_part,
    float* __restrict__ s_part, unsigned* __restrict__ counters,
    float* __restrict__ out, int C) {
  const int chunk = blockIdx.x;
  const int batch = blockIdx.y;
  const int tid   = threadIdx.x;
  const int lane  = tid & 63;
  const int wave  = tid >> 6;
  const int half  = lane >> 5;   // which of the 2 rows this lane handles
  const int l32   = lane & 31;   // d-group: d = l32*4 .. l32*4+3
  const int tPer  = T_DIM / C;
  const int t0    = chunk * tPer;

  const float4 wv = ((const float4*)W)[l32];
  const float* xb = x + (size_t)batch * (T_DIM * D_DIM);

  float4 o = make_float4(0.f, 0.f, 0.f, 0.f);
  float  s = 0.f;

#pragma unroll 4
  for (int t = t0 + wave * 2; t < t0 + tPer; t += NWAVES * 2) {
    const float4 xv = ((const float4*)(xb + (size_t)t * D_DIM))[lane];
    // row dot: lane holds 4 elements of row (t+half)
    float dot = xv.x * wv.x + xv.y * wv.y + xv.z * wv.z + xv.w * wv.w;
    dot += __shfl_xor(dot, 1);
    dot += __shfl_xor(dot, 2);
    dot += __shfl_xor(dot, 4);
    dot += __shfl_xor(dot, 8);
    dot += __shfl_xor(dot, 16);
    const float v   = dot + bb[t + half];
    // NaN-safe tanh: e2x=inf -> th -> 1; e2x=0 -> th -> -1
    const float e2x = __expf(2.0f * v);
    const float th  = 1.0f - __fdividef(2.0f, e2x + 1.0f);
    const float p   = __expf(th);
    s += p;
    o.x += p * xv.x;
    o.y += p * xv.y;
    o.z += p * xv.z;
    o.w += p * xv.w;
  }

  // block reduce across NWAVES*2 (wave, half) accumulators
  __shared__ float o_lds[NWAVES * 2][D_DIM];
  __shared__ float s_lds[NWAVES * 2];
  ((float4*)o_lds[wave * 2 + half])[l32] = o;
  if (l32 == 0) s_lds[wave * 2 + half] = s;
  __syncthreads();

  if (FINAL) {
    if (tid < D_DIM) {
      float osum = 0.f;
#pragma unroll
      for (int i = 0; i < NWAVES * 2; ++i) osum += o_lds[i][tid];
      float st = 0.f;
#pragma unroll
      for (int i = 0; i < NWAVES * 2; ++i) st += s_lds[i];
      out[(size_t)batch * D_DIM + tid] = osum / st;
    }
    return;
  }

  // write this block's partial
  if (tid < D_DIM) {
    float osum = 0.f;
#pragma unroll
    for (int i = 0; i < NWAVES * 2; ++i) osum += o_lds[i][tid];
    o_part[((size_t)batch * C + chunk) * D_DIM + tid] = osum;
    if (tid == 0) {
      float st = 0.f;
#pragma unroll
      for (int i = 0; i < NWAVES * 2; ++i) st += s_lds[i];
      s_part[batch * C + chunk] = st;
    }
  }
  __syncthreads();  // all waves drain their stores (vmcnt(0) before barrier)

  // last block per batch finalizes
  __shared__ unsigned is_last;
  if (tid == 0) {
    __threadfence();  // release: make this block's partials device-visible
    is_last = (atomicAdd(&counters[batch], 1u) == (unsigned)(C - 1)) ? 1u : 0u;
  }
  __syncthreads();

  if (is_last && tid < D_DIM) {
    __threadfence();  // acquire: see all other blocks' partials
    float osum = 0.f;
#pragma unroll
    for (int c = 0; c < 8; ++c)
      osum += o_part[((size_t)batch * C + c) * D_DIM + tid];
    float st = 0.f;
#pragma unroll
    for (int c = 0; c < 8; ++c) st += s_part[batch * C + c];
    out[(size_t)batch * D_DIM + tid] = osum / st;
  }
}

extern "C" void kernel_launch(void* const* d_in, const int* in_sizes, int n_in,
                              void* d_out, int out_size, void* d_ws,
                              size_t ws_size, hipStream_t stream) {
  const float* x  = (const float*)d_in[0];
  const float* W  = (const float*)d_in[1];
  const float* bb = (const float*)d_in[2];
  float* out      = (float*)d_out;

  const int C = 8;  // t-chunks per batch -> 2048 blocks = 8/CU, full occupancy
  const size_t need =
      (size_t)B_DIM * C * (D_DIM + 1) * sizeof(float) + B_DIM * sizeof(unsigned);

  if (ws_size >= need) {
    float* o_part = (float*)d_ws;                          // [B, C, 128]
    float* s_part = o_part + (size_t)B_DIM * C * D_DIM;    // [B, C]
    unsigned* counters = (unsigned*)(s_part + (size_t)B_DIM * C);  // [B]
    hipMemsetAsync(counters, 0, B_DIM * sizeof(unsigned), stream);
    dim3 grid(C, B_DIM);
    attn_pass1<4, false><<<grid, 256, 0, stream>>>(x, W, bb, o_part, s_part,
                                                   counters, out, C);
  } else {
    // fallback: no workspace -> one block per batch, finalize in-kernel
    dim3 grid(1, B_DIM);
    attn_pass1<16, true><<<grid, 1024, 0, stream>>>(x, W, bb, nullptr, nullptr,
                                                    nullptr, out, 1);
  }
}

// Round 3
// 44.950 us; speedup vs baseline: 2.7107x; 2.7107x over previous
//
#include <hip/hip_runtime.h>

#define B_DIM 256
#define T_DIM 2048
#define D_DIM 128
#define NWAVES 16  // 1024 threads -> one block per batch, one block per CU

// Single fused kernel, one block = one batch. Single streaming pass over x:
//   p_t = exp(tanh(x[t,:]·W + b[t]))   (tanh in [-1,1] -> no softmax max needed)
//   s   = sum_t p_t ; o[d] = sum_t p_t * x[t,d] ; out = o/s
// Each lane float4-loads 16B: a wave covers TWO t-rows per load instruction
// (lanes 0-31 -> row t, lanes 32-63 -> row t+1). Row dot reduced with 5
// shfl_xor steps (stays inside each 32-lane half). Per-lane float4 "o" acc.
// No workspace, no atomics, no device-scope fences (R2 showed those cost
// ~150us in L2 writeback/invalidate serialization on CDNA4).
__global__ __launch_bounds__(NWAVES * 64) void attn_fused(
    const float* __restrict__ x, const float* __restrict__ W,
    const float* __restrict__ bb, float* __restrict__ out) {
  const int batch = blockIdx.x;
  const int tid   = threadIdx.x;
  const int lane  = tid & 63;
  const int wave  = tid >> 6;
  const int half  = lane >> 5;   // which of the 2 rows this lane handles
  const int l32   = lane & 31;   // d-group: d = l32*4 .. l32*4+3

  const float4 wv = ((const float4*)W)[l32];
  const float* xb = x + (size_t)batch * (T_DIM * D_DIM);

  float4 o = make_float4(0.f, 0.f, 0.f, 0.f);
  float  s = 0.f;

#pragma unroll 8
  for (int t = wave * 2; t < T_DIM; t += NWAVES * 2) {
    const float4 xv = ((const float4*)(xb + (size_t)t * D_DIM))[lane];
    // row dot: lane holds 4 elements of row (t+half)
    float dot = xv.x * wv.x + xv.y * wv.y + xv.z * wv.z + xv.w * wv.w;
    dot += __shfl_xor(dot, 1);
    dot += __shfl_xor(dot, 2);
    dot += __shfl_xor(dot, 4);
    dot += __shfl_xor(dot, 8);
    dot += __shfl_xor(dot, 16);
    const float v   = dot + bb[t + half];
    // NaN-safe tanh: e2x=inf -> th -> 1; e2x=0 -> th -> -1
    const float e2x = __expf(2.0f * v);
    const float th  = 1.0f - __fdividef(2.0f, e2x + 1.0f);
    const float p   = __expf(th);
    s += p;
    o.x += p * xv.x;
    o.y += p * xv.y;
    o.z += p * xv.z;
    o.w += p * xv.w;
  }

  // block reduce across NWAVES*2 (wave, half) accumulators, fixed order
  __shared__ float o_lds[NWAVES * 2][D_DIM];
  __shared__ float s_lds[NWAVES * 2];
  ((float4*)o_lds[wave * 2 + half])[l32] = o;
  if (l32 == 0) s_lds[wave * 2 + half] = s;
  __syncthreads();

  if (tid < D_DIM) {
    float osum = 0.f;
#pragma unroll
    for (int i = 0; i < NWAVES * 2; ++i) osum += o_lds[i][tid];
    float st = 0.f;
#pragma unroll
    for (int i = 0; i < NWAVES * 2; ++i) st += s_lds[i];
    out[(size_t)batch * D_DIM + tid] = osum / st;
  }
}

extern "C" void kernel_launch(void* const* d_in, const int* in_sizes, int n_in,
                              void* d_out, int out_size, void* d_ws,
                              size_t ws_size, hipStream_t stream) {
  const float* x  = (const float*)d_in[0];
  const float* W  = (const float*)d_in[1];
  const float* bb = (const float*)d_in[2];
  float* out      = (float*)d_out;
  attn_fused<<<B_DIM, NWAVES * 64, 0, stream>>>(x, W, bb, out);
}